// Round 5
// baseline (418.695 us; speedup 1.0000x reference)
//
#include <hip/hip_runtime.h>
#include <hip/hip_cooperative_groups.h>
#include <math.h>

namespace cg = cooperative_groups;

#define NN 8192
#define FIN 512
#define HD 128
#define CAP 128
#define GEMM_B 512   // fallback kernel: blocks [0,512) GEMM
#define ADJ_B  2048

// ===========================================================================
// Monolithic cooperative kernel: 4 phases separated by grid.sync().
//   A: blocks [0,GB): dual GEMM xl=x@Wl1, xr=x@Wr1 (32-row tiles, shared As)
//      blocks [GB,nb): adjacency scan -> nbr/degi/degf; block nb-1 also folds
//      wsm = {Wl2@Wd, Wr2@Wd, b2@Wd+bd}
//   B: per-wave row i: h=relu(mean_j xl[j]+xr[i]+b1); u=h@Wld, v=h@Wrd
//   C: y[i] = mean_j u[j] + v[i] + c
//   D: out[i,j] = ||y_i - y_j||  (32i x 1024j tiles)
// ===========================================================================
__global__ __launch_bounds__(256, 4) void k_mono(
    const float* __restrict__ x, const float* __restrict__ Wl1,
    const float* __restrict__ Wr1, const float* __restrict__ adj,
    const float* __restrict__ b1, const float* __restrict__ Wl2,
    const float* __restrict__ Wr2, const float* __restrict__ b2,
    const float* __restrict__ Wd, const float* __restrict__ bd,
    float* __restrict__ xl, float* __restrict__ xr,
    int* __restrict__ nbr, int* __restrict__ degi, float* __restrict__ degf,
    float4* __restrict__ u4, float4* __restrict__ v4, float4* __restrict__ y4,
    float4* __restrict__ wsm, float* __restrict__ out)
{
    __shared__ union {
        struct { float As[32][32]; float Bl[32][128]; float Br[32][128]; } g;
        int lists[4][CAP];
        float4 yis[32];
    } sh;   // 36 KB -> 4 blocks/CU

    cg::grid_group gg = cg::this_grid();
    const int tid = threadIdx.x;
    const int bid = blockIdx.x;
    const int nb  = gridDim.x;
    const int GB  = (nb / 2 < 256) ? nb / 2 : 256;

    // ======================= phase A =======================
    if (bid < GB) {
        const int rg = tid >> 5, cg2 = tid & 31;
        const int ar = tid >> 3, ak = (tid & 7) * 4;
        const int bk = tid >> 5, bc = (tid & 31) * 4;
        for (int t = bid; t < NN / 32; t += GB) {
            const int row0 = t * 32;
            float accl[4][4] = {}, accr[4][4] = {};
            for (int ch = 0; ch < FIN / 32; ++ch) {
                const int kc = ch * 32;
                __syncthreads();
                const float4 va = *(const float4*)(x + (size_t)(row0 + ar) * FIN + kc + ak);
                sh.g.As[ak + 0][ar] = va.x; sh.g.As[ak + 1][ar] = va.y;
                sh.g.As[ak + 2][ar] = va.z; sh.g.As[ak + 3][ar] = va.w;
                #pragma unroll
                for (int it = 0; it < 4; ++it) {
                    *(float4*)&sh.g.Bl[bk + 8 * it][bc] =
                        *(const float4*)(Wl1 + (size_t)(kc + bk + 8 * it) * HD + bc);
                    *(float4*)&sh.g.Br[bk + 8 * it][bc] =
                        *(const float4*)(Wr1 + (size_t)(kc + bk + 8 * it) * HD + bc);
                }
                __syncthreads();
                #pragma unroll
                for (int k = 0; k < 32; ++k) {
                    const float4 a4  = *(const float4*)&sh.g.As[k][rg * 4];
                    const float4 bl4 = *(const float4*)&sh.g.Bl[k][cg2 * 4];
                    const float4 br4 = *(const float4*)&sh.g.Br[k][cg2 * 4];
                    const float av[4]  = {a4.x, a4.y, a4.z, a4.w};
                    const float blv[4] = {bl4.x, bl4.y, bl4.z, bl4.w};
                    const float brv[4] = {br4.x, br4.y, br4.z, br4.w};
                    #pragma unroll
                    for (int a = 0; a < 4; ++a)
                        #pragma unroll
                        for (int b = 0; b < 4; ++b) {
                            accl[a][b] = fmaf(av[a], blv[b], accl[a][b]);
                            accr[a][b] = fmaf(av[a], brv[b], accr[a][b]);
                        }
                }
            }
            #pragma unroll
            for (int a = 0; a < 4; ++a) {
                *(float4*)(xl + (size_t)(row0 + rg * 4 + a) * HD + cg2 * 4) =
                    make_float4(accl[a][0], accl[a][1], accl[a][2], accl[a][3]);
                *(float4*)(xr + (size_t)(row0 + rg * 4 + a) * HD + cg2 * 4) =
                    make_float4(accr[a][0], accr[a][1], accr[a][2], accr[a][3]);
            }
        }
    } else {
        const int w = tid >> 6, lane = tid & 63;
        const unsigned long long lmask = (1ull << lane) - 1ull;
        for (int u = bid - GB; u < NN / 4; u += nb - GB) {
            const int i = u * 4 + w;
            int* lst = nbr + (size_t)i * CAP;
            const float4* row = (const float4*)(adj + (size_t)i * NN);
            int cnt = 0;
            for (int it = 0; it < NN / 256; ++it) {
                const float4 a = row[it * 64 + lane];
                const float vals[4] = {a.x, a.y, a.z, a.w};
                #pragma unroll
                for (int e = 0; e < 4; ++e) {
                    const bool nz = (vals[e] != 0.0f);
                    const unsigned long long m = __ballot(nz);
                    if (nz) {
                        const int p = cnt + (int)__popcll(m & lmask);
                        if (p < CAP) lst[p] = (it * 64 + lane) * 4 + e;
                    }
                    cnt += (int)__popcll(m);
                }
            }
            if (lane == 0) {
                degi[i] = cnt < CAP ? cnt : CAP;
                degf[i] = fmaxf((float)cnt, 1.0f);
            }
        }
        if (bid == nb - 1 && tid < HD) {
            const int t = tid;
            float l0 = 0, l1 = 0, l2 = 0, r0 = 0, r1 = 0, r2 = 0;
            for (int c = 0; c < HD; ++c) {
                const float w0 = Wd[c * 3 + 0], w1 = Wd[c * 3 + 1], w2 = Wd[c * 3 + 2];
                const float wl = Wl2[t * HD + c];
                const float wr = Wr2[t * HD + c];
                l0 = fmaf(wl, w0, l0); l1 = fmaf(wl, w1, l1); l2 = fmaf(wl, w2, l2);
                r0 = fmaf(wr, w0, r0); r1 = fmaf(wr, w1, r1); r2 = fmaf(wr, w2, r2);
            }
            wsm[t]       = make_float4(l0, l1, l2, 0.f);
            wsm[128 + t] = make_float4(r0, r1, r2, 0.f);
            if (t == 0) {
                float c0 = bd[0], c1 = bd[1], c2 = bd[2];
                for (int c = 0; c < HD; ++c) {
                    c0 = fmaf(b2[c], Wd[c * 3 + 0], c0);
                    c1 = fmaf(b2[c], Wd[c * 3 + 1], c1);
                    c2 = fmaf(b2[c], Wd[c * 3 + 2], c2);
                }
                wsm[256] = make_float4(c0, c1, c2, 0.f);
            }
        }
    }
    gg.sync();

    // ======================= phase B =======================
    {
        const int w = tid >> 6, lane = tid & 63;
        int* lst = sh.lists[w];
        for (int q = bid; q < NN / 4; q += nb) {
            const int i = q * 4 + w;
            const int d = degi[i];
            const float inv = 1.0f / degf[i];
            const int* glst = nbr + (size_t)i * CAP;
            if (lane < d)      lst[lane]      = glst[lane];
            if (lane + 64 < d) lst[lane + 64] = glst[lane + 64];

            float s0 = 0.f, s1 = 0.f;
            int t = 0;
            for (; t + 4 <= d; t += 4) {
                const int j0 = lst[t], j1 = lst[t + 1], j2 = lst[t + 2], j3 = lst[t + 3];
                const float2 a0 = ((const float2*)(xl + (size_t)j0 * HD))[lane];
                const float2 a1 = ((const float2*)(xl + (size_t)j1 * HD))[lane];
                const float2 a2 = ((const float2*)(xl + (size_t)j2 * HD))[lane];
                const float2 a3 = ((const float2*)(xl + (size_t)j3 * HD))[lane];
                s0 += a0.x + a1.x + a2.x + a3.x;
                s1 += a0.y + a1.y + a2.y + a3.y;
            }
            for (; t < d; ++t) {
                const float2 a0 = ((const float2*)(xl + (size_t)lst[t] * HD))[lane];
                s0 += a0.x; s1 += a0.y;
            }

            const float2 rr = ((const float2*)(xr + (size_t)i * HD))[lane];
            const float2 bb = ((const float2*)b1)[lane];
            const float h0 = fmaxf(fmaf(s0, inv, rr.x + bb.x), 0.f);
            const float h1 = fmaxf(fmaf(s1, inv, rr.y + bb.y), 0.f);
            const float4 w0 = wsm[2 * lane], w1 = wsm[2 * lane + 1];
            const float4 q0 = wsm[128 + 2 * lane], q1 = wsm[128 + 2 * lane + 1];
            float u0 = h0 * w0.x + h1 * w1.x;
            float u1 = h0 * w0.y + h1 * w1.y;
            float u2 = h0 * w0.z + h1 * w1.z;
            float v0 = h0 * q0.x + h1 * q1.x;
            float v1 = h0 * q0.y + h1 * q1.y;
            float v2 = h0 * q0.z + h1 * q1.z;
            #pragma unroll
            for (int off = 32; off; off >>= 1) {
                u0 += __shfl_xor(u0, off); u1 += __shfl_xor(u1, off); u2 += __shfl_xor(u2, off);
                v0 += __shfl_xor(v0, off); v1 += __shfl_xor(v1, off); v2 += __shfl_xor(v2, off);
            }
            if (lane == 0) {
                u4[i] = make_float4(u0, u1, u2, 0.f);
                v4[i] = make_float4(v0, v1, v2, 0.f);
            }
        }
    }
    gg.sync();

    // ======================= phase C =======================
    {
        const int hw = tid >> 5, lane = tid & 31;
        for (int q = bid; q < NN / 8; q += nb) {
            const int i = q * 8 + hw;
            const int d = degi[i];
            const float inv = 1.0f / degf[i];
            const int* lst = nbr + (size_t)i * CAP;
            float s0 = 0.f, s1 = 0.f, s2 = 0.f;
            for (int base = 0; base + lane < d; base += 32) {
                const float4 u = u4[lst[base + lane]];
                s0 += u.x; s1 += u.y; s2 += u.z;
            }
            #pragma unroll
            for (int off = 16; off; off >>= 1) {
                s0 += __shfl_xor(s0, off); s1 += __shfl_xor(s1, off); s2 += __shfl_xor(s2, off);
            }
            if (lane == 0) {
                const float4 v = v4[i];
                const float4 c = wsm[256];
                y4[i] = make_float4(fmaf(s0, inv, v.x + c.x),
                                    fmaf(s1, inv, v.y + c.y),
                                    fmaf(s2, inv, v.z + c.z), 0.f);
            }
        }
    }
    gg.sync();

    // ======================= phase D =======================
    for (int t = bid; t < (NN / 32) * (NN / 1024); t += nb) {
        const int i0 = (t >> 3) * 32;
        const int jb = (t & 7) * 1024 + tid * 4;
        __syncthreads();
        if (tid < 32) sh.yis[tid] = y4[i0 + tid];
        __syncthreads();
        const float4 a0 = y4[jb + 0], a1 = y4[jb + 1];
        const float4 a2 = y4[jb + 2], a3 = y4[jb + 3];
        float* op = out + (size_t)i0 * NN + jb;
        #pragma unroll 4
        for (int ii = 0; ii < 32; ++ii) {
            const float4 yi = sh.yis[ii];
            float4 r;
            { const float dx = yi.x - a0.x, dy = yi.y - a0.y, dz = yi.z - a0.z;
              r.x = sqrtf(fmaf(dx, dx, fmaf(dy, dy, dz * dz))); }
            { const float dx = yi.x - a1.x, dy = yi.y - a1.y, dz = yi.z - a1.z;
              r.y = sqrtf(fmaf(dx, dx, fmaf(dy, dy, dz * dz))); }
            { const float dx = yi.x - a2.x, dy = yi.y - a2.y, dz = yi.z - a2.z;
              r.z = sqrtf(fmaf(dx, dx, fmaf(dy, dy, dz * dz))); }
            { const float dx = yi.x - a3.x, dy = yi.y - a3.y, dz = yi.z - a3.z;
              r.w = sqrtf(fmaf(dx, dx, fmaf(dy, dy, dz * dz))); }
            *(float4*)op = r;
            op += NN;
        }
    }
}

// ===========================================================================
// Fallback pipeline (round-4, proven): used when cooperative launch is
// unavailable. Deterministic: branch depends only on device capability.
// ===========================================================================
__global__ __launch_bounds__(256) void k_front(
    const float* __restrict__ x, const float* __restrict__ Wl1,
    const float* __restrict__ Wr1, const float* __restrict__ adj,
    const float* __restrict__ Wl2, const float* __restrict__ Wr2,
    const float* __restrict__ b2, const float* __restrict__ Wd,
    const float* __restrict__ bd,
    float* __restrict__ xl, float* __restrict__ xr,
    int* __restrict__ nbr, int* __restrict__ degi, float* __restrict__ degf,
    float4* __restrict__ wsm)
{
    __shared__ float As[32][32];
    __shared__ float Bs[32][128];
    const int tid = threadIdx.x;

    if (blockIdx.x < GEMM_B) {
        const float* W = (blockIdx.x < 256) ? Wl1 : Wr1;
        float* Cout    = (blockIdx.x < 256) ? xl  : xr;
        const int row0 = (blockIdx.x & 255) * 32;
        const int rg = tid >> 5, cg = tid & 31;
        const int ar = tid >> 3, ak = (tid & 7) * 4;
        const int bk = tid >> 5, bc = (tid & 31) * 4;
        float acc[4][4] = {};
        for (int ch = 0; ch < FIN / 32; ++ch) {
            const int kc = ch * 32;
            __syncthreads();
            const float4 va = *(const float4*)(x + (size_t)(row0 + ar) * FIN + kc + ak);
            As[ak + 0][ar] = va.x; As[ak + 1][ar] = va.y;
            As[ak + 2][ar] = va.z; As[ak + 3][ar] = va.w;
            #pragma unroll
            for (int it = 0; it < 4; ++it)
                *(float4*)&Bs[bk + 8 * it][bc] =
                    *(const float4*)(W + (size_t)(kc + bk + 8 * it) * HD + bc);
            __syncthreads();
            #pragma unroll
            for (int k = 0; k < 32; ++k) {
                const float4 a4 = *(const float4*)&As[k][rg * 4];
                const float4 b4 = *(const float4*)&Bs[k][cg * 4];
                const float av[4] = {a4.x, a4.y, a4.z, a4.w};
                const float bv[4] = {b4.x, b4.y, b4.z, b4.w};
                #pragma unroll
                for (int a = 0; a < 4; ++a)
                    #pragma unroll
                    for (int b = 0; b < 4; ++b)
                        acc[a][b] = fmaf(av[a], bv[b], acc[a][b]);
            }
        }
        #pragma unroll
        for (int a = 0; a < 4; ++a)
            *(float4*)(Cout + (size_t)(row0 + rg * 4 + a) * HD + cg * 4) =
                make_float4(acc[a][0], acc[a][1], acc[a][2], acc[a][3]);
    } else if (blockIdx.x < GEMM_B + ADJ_B) {
        const int w = tid >> 6, lane = tid & 63;
        const int i = (blockIdx.x - GEMM_B) * 4 + w;
        int* lst = nbr + (size_t)i * CAP;
        const float4* row = (const float4*)(adj + (size_t)i * NN);
        const unsigned long long lmask = (1ull << lane) - 1ull;
        int cnt = 0;
        for (int it = 0; it < NN / 256; ++it) {
            const float4 a = row[it * 64 + lane];
            const float vals[4] = {a.x, a.y, a.z, a.w};
            #pragma unroll
            for (int e = 0; e < 4; ++e) {
                const bool nz = (vals[e] != 0.0f);
                const unsigned long long m = __ballot(nz);
                if (nz) {
                    const int p = cnt + (int)__popcll(m & lmask);
                    if (p < CAP) lst[p] = (it * 64 + lane) * 4 + e;
                }
                cnt += (int)__popcll(m);
            }
        }
        if (lane == 0) {
            degi[i] = cnt < CAP ? cnt : CAP;
            degf[i] = fmaxf((float)cnt, 1.0f);
        }
    } else {
        const int t = tid;
        if (t < HD) {
            float l0 = 0, l1 = 0, l2 = 0, r0 = 0, r1 = 0, r2 = 0;
            for (int c = 0; c < HD; ++c) {
                const float w0 = Wd[c * 3 + 0], w1 = Wd[c * 3 + 1], w2 = Wd[c * 3 + 2];
                const float wl = Wl2[t * HD + c];
                const float wr = Wr2[t * HD + c];
                l0 = fmaf(wl, w0, l0); l1 = fmaf(wl, w1, l1); l2 = fmaf(wl, w2, l2);
                r0 = fmaf(wr, w0, r0); r1 = fmaf(wr, w1, r1); r2 = fmaf(wr, w2, r2);
            }
            wsm[t]       = make_float4(l0, l1, l2, 0.f);
            wsm[128 + t] = make_float4(r0, r1, r2, 0.f);
            if (t == 0) {
                float c0 = bd[0], c1 = bd[1], c2 = bd[2];
                for (int c = 0; c < HD; ++c) {
                    c0 = fmaf(b2[c], Wd[c * 3 + 0], c0);
                    c1 = fmaf(b2[c], Wd[c * 3 + 1], c1);
                    c2 = fmaf(b2[c], Wd[c * 3 + 2], c2);
                }
                wsm[256] = make_float4(c0, c1, c2, 0.f);
            }
        }
    }
}

__global__ __launch_bounds__(256) void k_agg_proj(
    const float* __restrict__ xl, const float* __restrict__ xr,
    const float* __restrict__ b1, const int* __restrict__ nbr,
    const int* __restrict__ degi, const float* __restrict__ degf,
    const float4* __restrict__ wsm, float4* __restrict__ u4,
    float4* __restrict__ v4)
{
    __shared__ int lists[4][CAP];
    const int w = threadIdx.x >> 6, lane = threadIdx.x & 63;
    const int i = blockIdx.x * 4 + w;
    const int d = degi[i];
    const float inv = 1.0f / degf[i];
    const int* glst = nbr + (size_t)i * CAP;
    if (lane < d)      lists[w][lane]      = glst[lane];
    if (lane + 64 < d) lists[w][lane + 64] = glst[lane + 64];
    const int* lst = lists[w];

    float s0 = 0.f, s1 = 0.f;
    int t = 0;
    for (; t + 4 <= d; t += 4) {
        const int j0 = lst[t], j1 = lst[t + 1], j2 = lst[t + 2], j3 = lst[t + 3];
        const float2 a0 = ((const float2*)(xl + (size_t)j0 * HD))[lane];
        const float2 a1 = ((const float2*)(xl + (size_t)j1 * HD))[lane];
        const float2 a2 = ((const float2*)(xl + (size_t)j2 * HD))[lane];
        const float2 a3 = ((const float2*)(xl + (size_t)j3 * HD))[lane];
        s0 += a0.x + a1.x + a2.x + a3.x;
        s1 += a0.y + a1.y + a2.y + a3.y;
    }
    for (; t < d; ++t) {
        const float2 a0 = ((const float2*)(xl + (size_t)lst[t] * HD))[lane];
        s0 += a0.x; s1 += a0.y;
    }

    const float2 rr = ((const float2*)(xr + (size_t)i * HD))[lane];
    const float2 bb = ((const float2*)b1)[lane];
    const float h0 = fmaxf(fmaf(s0, inv, rr.x + bb.x), 0.f);
    const float h1 = fmaxf(fmaf(s1, inv, rr.y + bb.y), 0.f);
    const float4 w0 = wsm[2 * lane], w1 = wsm[2 * lane + 1];
    const float4 q0 = wsm[128 + 2 * lane], q1 = wsm[128 + 2 * lane + 1];
    float u0 = h0 * w0.x + h1 * w1.x;
    float u1 = h0 * w0.y + h1 * w1.y;
    float u2 = h0 * w0.z + h1 * w1.z;
    float v0 = h0 * q0.x + h1 * q1.x;
    float v1 = h0 * q0.y + h1 * q1.y;
    float v2 = h0 * q0.z + h1 * q1.z;
    #pragma unroll
    for (int off = 32; off; off >>= 1) {
        u0 += __shfl_xor(u0, off); u1 += __shfl_xor(u1, off); u2 += __shfl_xor(u2, off);
        v0 += __shfl_xor(v0, off); v1 += __shfl_xor(v1, off); v2 += __shfl_xor(v2, off);
    }
    if (lane == 0) {
        u4[i] = make_float4(u0, u1, u2, 0.f);
        v4[i] = make_float4(v0, v1, v2, 0.f);
    }
}

__global__ __launch_bounds__(256) void k_ycomb(
    const float4* __restrict__ u4, const float4* __restrict__ v4,
    const int* __restrict__ nbr, const int* __restrict__ degi,
    const float* __restrict__ degf, const float4* __restrict__ wsm,
    float4* __restrict__ y4)
{
    const int hw = threadIdx.x >> 5;
    const int lane = threadIdx.x & 31;
    const int i = blockIdx.x * 8 + hw;
    const int d = degi[i];
    const float inv = 1.0f / degf[i];
    const int* lst = nbr + (size_t)i * CAP;
    float s0 = 0.f, s1 = 0.f, s2 = 0.f;
    for (int base = 0; base + lane < d; base += 32) {
        const float4 u = u4[lst[base + lane]];
        s0 += u.x; s1 += u.y; s2 += u.z;
    }
    #pragma unroll
    for (int off = 16; off; off >>= 1) {
        s0 += __shfl_xor(s0, off); s1 += __shfl_xor(s1, off); s2 += __shfl_xor(s2, off);
    }
    if (lane == 0) {
        const float4 v = v4[i];
        const float4 c = wsm[256];
        y4[i] = make_float4(fmaf(s0, inv, v.x + c.x),
                            fmaf(s1, inv, v.y + c.y),
                            fmaf(s2, inv, v.z + c.z), 0.f);
    }
}

__global__ __launch_bounds__(256) void k_cdist(
    const float4* __restrict__ y4, float* __restrict__ out)
{
    __shared__ float4 yis[32];
    const int t = threadIdx.x;
    const int i0 = blockIdx.y * 32;
    if (t < 32) yis[t] = y4[i0 + t];
    __syncthreads();
    const int j0 = blockIdx.x * 1024 + t * 4;
    const float4 a0 = y4[j0 + 0], a1 = y4[j0 + 1];
    const float4 a2 = y4[j0 + 2], a3 = y4[j0 + 3];
    float* op = out + (size_t)i0 * NN + j0;
    #pragma unroll 4
    for (int ii = 0; ii < 32; ++ii) {
        const float4 yi = yis[ii];
        float4 r;
        { const float dx = yi.x - a0.x, dy = yi.y - a0.y, dz = yi.z - a0.z;
          r.x = sqrtf(fmaf(dx, dx, fmaf(dy, dy, dz * dz))); }
        { const float dx = yi.x - a1.x, dy = yi.y - a1.y, dz = yi.z - a1.z;
          r.y = sqrtf(fmaf(dx, dx, fmaf(dy, dy, dz * dz))); }
        { const float dx = yi.x - a2.x, dy = yi.y - a2.y, dz = yi.z - a2.z;
          r.z = sqrtf(fmaf(dx, dx, fmaf(dy, dy, dz * dz))); }
        { const float dx = yi.x - a3.x, dy = yi.y - a3.y, dz = yi.z - a3.z;
          r.w = sqrtf(fmaf(dx, dx, fmaf(dy, dy, dz * dz))); }
        *(float4*)op = r;
        op += NN;
    }
}

// ---------------------------------------------------------------------------
extern "C" void kernel_launch(void* const* d_in, const int* in_sizes, int n_in,
                              void* d_out, int out_size, void* d_ws, size_t ws_size,
                              hipStream_t stream) {
    const float* x   = (const float*)d_in[0];
    const float* adj = (const float*)d_in[1];
    const float* Wl1 = (const float*)d_in[2];
    const float* Wr1 = (const float*)d_in[3];
    const float* b1  = (const float*)d_in[4];
    const float* Wl2 = (const float*)d_in[5];
    const float* Wr2 = (const float*)d_in[6];
    const float* b2  = (const float*)d_in[7];
    const float* Wd  = (const float*)d_in[8];
    const float* bd  = (const float*)d_in[9];
    float* out = (float*)d_out;

    // ---- workspace layout ----
    char* ws = (char*)d_ws;
    const size_t nbr_b  = (size_t)NN * CAP * 4;
    const size_t deg_b  = (size_t)NN * 4;
    const size_t vec_b  = (size_t)NN * 16;
    const size_t wsm_b  = 272 * 16;
    const size_t small_total = nbr_b + 2 * deg_b + 3 * vec_b + wsm_b;
    const size_t xl_b = (size_t)NN * HD * 4;

    size_t off = 0;
    int*    nbr  = (int*)(ws + off);    off += nbr_b;
    int*    degi = (int*)(ws + off);    off += deg_b;
    float*  degf = (float*)(ws + off);  off += deg_b;
    float4* u4   = (float4*)(ws + off); off += vec_b;
    float4* v4   = (float4*)(ws + off); off += vec_b;
    float4* y4   = (float4*)(ws + off); off += vec_b;
    float4* wsm  = (float4*)(ws + off); off += wsm_b;
    char* big = (ws_size >= small_total + 2 * xl_b) ? (ws + off) : (char*)d_out;
    float* xl = (float*)(big);
    float* xr = (float*)(big + xl_b);

    // ---- cooperative mono-kernel if supported (host-side queries only) ----
    int dev = 0;
    (void)hipGetDevice(&dev);
    int coop = 0;
    (void)hipDeviceGetAttribute(&coop, hipDeviceAttributeCooperativeLaunch, dev);
    int ncu = 0;
    (void)hipDeviceGetAttribute(&ncu, hipDeviceAttributeMultiprocessorCount, dev);
    if (ncu <= 0) ncu = 256;
    int maxb = 0;
    if (coop) {
        if (hipOccupancyMaxActiveBlocksPerMultiprocessor(&maxb, k_mono, 256, 0)
            != hipSuccess) maxb = 0;
    }
    long grid = (long)maxb * ncu;
    if (grid > 1024) grid = 1024;

    if (coop && grid >= 512) {
        void* args[] = {
            (void*)&x, (void*)&Wl1, (void*)&Wr1, (void*)&adj, (void*)&b1,
            (void*)&Wl2, (void*)&Wr2, (void*)&b2, (void*)&Wd, (void*)&bd,
            (void*)&xl, (void*)&xr, (void*)&nbr, (void*)&degi, (void*)&degf,
            (void*)&u4, (void*)&v4, (void*)&y4, (void*)&wsm, (void*)&out
        };
        hipError_t e = hipLaunchCooperativeKernel(
            k_mono, dim3((unsigned)grid), dim3(256), args, 0u, stream);
        if (e == hipSuccess) return;
    }

    // ---- fallback: proven 4-kernel pipeline ----
    k_front<<<GEMM_B + ADJ_B + 1, 256, 0, stream>>>(
        x, Wl1, Wr1, adj, Wl2, Wr2, b2, Wd, bd,
        xl, xr, nbr, degi, degf, wsm);
    k_agg_proj<<<NN / 4, 256, 0, stream>>>(xl, xr, b1, nbr, degi, degf,
                                           wsm, u4, v4);
    k_ycomb<<<NN / 8, 256, 0, stream>>>(u4, v4, nbr, degi, degf, wsm, y4);
    k_cdist<<<dim3(NN / 1024, NN / 32), 256, 0, stream>>>(y4, out);
}

// Round 7
// 146.201 us; speedup vs baseline: 2.8638x; 2.8638x over previous
//
#include <hip/hip_runtime.h>
#include <math.h>

#define NN 8192
#define FIN 512
#define HD 128
#define CAP 128

typedef float f32x4 __attribute__((ext_vector_type(4)));

// ---------------------------------------------------------------------------
// K1 "front": heterogeneous kernel, block-granular INTERLEAVED split so every
// CU hosts both kinds of work (VALU-bound GEMM overlaps HBM-bound scan):
//   blocks with b%5==0 (512): GEMM tile of xl = x@Wl1 (gi<256) or xr = x@Wr1
//   all other blocks (2048):  adjacency scan -> nbr/degi/degf (1 row/wave)
//   block 2560:               fold wsm = {Wl2@Wd, Wr2@Wd, b2@Wd+bd}
// ---------------------------------------------------------------------------
__global__ __launch_bounds__(256) void k_front(
    const float* __restrict__ x, const float* __restrict__ Wl1,
    const float* __restrict__ Wr1, const float* __restrict__ adj,
    const float* __restrict__ Wl2, const float* __restrict__ Wr2,
    const float* __restrict__ b2, const float* __restrict__ Wd,
    const float* __restrict__ bd,
    float* __restrict__ xl, float* __restrict__ xr,
    int* __restrict__ nbr, int* __restrict__ degi, float* __restrict__ degf,
    float4* __restrict__ wsm)
{
    __shared__ float As[32][32];
    __shared__ float Bs[32][128];
    const int tid = threadIdx.x;
    const int b = blockIdx.x;

    if (b == 2560) {
        // ---------------- fold small weights ----------------
        const int t = tid;
        if (t < HD) {
            float l0 = 0, l1 = 0, l2 = 0, r0 = 0, r1 = 0, r2 = 0;
            for (int c = 0; c < HD; ++c) {
                const float w0 = Wd[c * 3 + 0], w1 = Wd[c * 3 + 1], w2 = Wd[c * 3 + 2];
                const float wl = Wl2[t * HD + c];
                const float wr = Wr2[t * HD + c];
                l0 = fmaf(wl, w0, l0); l1 = fmaf(wl, w1, l1); l2 = fmaf(wl, w2, l2);
                r0 = fmaf(wr, w0, r0); r1 = fmaf(wr, w1, r1); r2 = fmaf(wr, w2, r2);
            }
            wsm[t]       = make_float4(l0, l1, l2, 0.f);
            wsm[128 + t] = make_float4(r0, r1, r2, 0.f);
            if (t == 0) {
                float c0 = bd[0], c1 = bd[1], c2 = bd[2];
                for (int c = 0; c < HD; ++c) {
                    c0 = fmaf(b2[c], Wd[c * 3 + 0], c0);
                    c1 = fmaf(b2[c], Wd[c * 3 + 1], c1);
                    c2 = fmaf(b2[c], Wd[c * 3 + 2], c2);
                }
                wsm[256] = make_float4(c0, c1, c2, 0.f);
            }
        }
    } else if (b % 5 == 0) {
        // ---------------- GEMM: 32x128 tile, K=512 ----------------
        const int gi = b / 5;                       // 0..511
        const float* W = (gi < 256) ? Wl1 : Wr1;
        float* Cout    = (gi < 256) ? xl  : xr;
        const int row0 = (gi & 255) * 32;
        const int rg = tid >> 5, cg = tid & 31;
        const int ar = tid >> 3, ak = (tid & 7) * 4;
        const int bk = tid >> 5, bc = (tid & 31) * 4;
        float acc[4][4] = {};
        for (int ch = 0; ch < FIN / 32; ++ch) {
            const int kc = ch * 32;
            __syncthreads();
            const float4 va = *(const float4*)(x + (size_t)(row0 + ar) * FIN + kc + ak);
            As[ak + 0][ar] = va.x; As[ak + 1][ar] = va.y;
            As[ak + 2][ar] = va.z; As[ak + 3][ar] = va.w;
            #pragma unroll
            for (int it = 0; it < 4; ++it)
                *(float4*)&Bs[bk + 8 * it][bc] =
                    *(const float4*)(W + (size_t)(kc + bk + 8 * it) * HD + bc);
            __syncthreads();
            #pragma unroll
            for (int k = 0; k < 32; ++k) {
                const float4 a4 = *(const float4*)&As[k][rg * 4];
                const float4 b4 = *(const float4*)&Bs[k][cg * 4];
                const float av[4] = {a4.x, a4.y, a4.z, a4.w};
                const float bv[4] = {b4.x, b4.y, b4.z, b4.w};
                #pragma unroll
                for (int a = 0; a < 4; ++a)
                    #pragma unroll
                    for (int bb = 0; bb < 4; ++bb)
                        acc[a][bb] = fmaf(av[a], bv[bb], acc[a][bb]);
            }
        }
        #pragma unroll
        for (int a = 0; a < 4; ++a)
            *(float4*)(Cout + (size_t)(row0 + rg * 4 + a) * HD + cg * 4) =
                make_float4(acc[a][0], acc[a][1], acc[a][2], acc[a][3]);
    } else {
        // ---------------- adjacency scan: 1 row per 64-lane wave ----------
        const int si = b - b / 5 - 1;               // 0..2047 scan block index
        const int w = tid >> 6, lane = tid & 63;
        const int i = si * 4 + w;
        int* lst = nbr + (size_t)i * CAP;
        const f32x4* row = (const f32x4*)(adj + (size_t)i * NN);
        const unsigned long long lmask = (1ull << lane) - 1ull;
        int cnt = 0;
        for (int it = 0; it < NN / 256; ++it) {   // 32 iters, 1 KB/wave each
            const f32x4 a = __builtin_nontemporal_load(&row[it * 64 + lane]);
            const float vals[4] = {a.x, a.y, a.z, a.w};
            #pragma unroll
            for (int e = 0; e < 4; ++e) {
                const bool nz = (vals[e] != 0.0f);
                const unsigned long long m = __ballot(nz);
                if (nz) {
                    const int p = cnt + (int)__popcll(m & lmask);
                    if (p < CAP) lst[p] = (it * 64 + lane) * 4 + e;
                }
                cnt += (int)__popcll(m);
            }
        }
        if (lane == 0) {
            degi[i] = cnt < CAP ? cnt : CAP;
            degf[i] = fmaxf((float)cnt, 1.0f);
        }
    }
}

// ---------------------------------------------------------------------------
// K2: one 64-lane wave per row i (cols 2*lane, 2*lane+1):
//   h = relu(mean_j xl[j,:] + xr[i,:] + b1)   (in registers)
//   u[i] = h @ Wld, v[i] = h @ Wrd            (butterfly-reduced 3-vectors)
// ---------------------------------------------------------------------------
__global__ __launch_bounds__(256) void k_agg_proj(
    const float* __restrict__ xl, const float* __restrict__ xr,
    const float* __restrict__ b1, const int* __restrict__ nbr,
    const int* __restrict__ degi, const float* __restrict__ degf,
    const float4* __restrict__ wsm, float4* __restrict__ u4,
    float4* __restrict__ v4)
{
    __shared__ int lists[4][CAP];
    const int w = threadIdx.x >> 6, lane = threadIdx.x & 63;
    const int i = blockIdx.x * 4 + w;
    const int d = degi[i];
    const float inv = 1.0f / degf[i];
    const int* glst = nbr + (size_t)i * CAP;
    if (lane < d)      lists[w][lane]      = glst[lane];
    if (lane + 64 < d) lists[w][lane + 64] = glst[lane + 64];
    const int* lst = lists[w];   // wave-local producer/consumer: lgkmcnt suffices

    float s0 = 0.f, s1 = 0.f;
    int t = 0;
    for (; t + 4 <= d; t += 4) {
        const int j0 = lst[t], j1 = lst[t + 1], j2 = lst[t + 2], j3 = lst[t + 3];
        const float2 a0 = ((const float2*)(xl + (size_t)j0 * HD))[lane];
        const float2 a1 = ((const float2*)(xl + (size_t)j1 * HD))[lane];
        const float2 a2 = ((const float2*)(xl + (size_t)j2 * HD))[lane];
        const float2 a3 = ((const float2*)(xl + (size_t)j3 * HD))[lane];
        s0 += a0.x + a1.x + a2.x + a3.x;
        s1 += a0.y + a1.y + a2.y + a3.y;
    }
    for (; t < d; ++t) {
        const float2 a0 = ((const float2*)(xl + (size_t)lst[t] * HD))[lane];
        s0 += a0.x; s1 += a0.y;
    }

    const float2 rr = ((const float2*)(xr + (size_t)i * HD))[lane];
    const float2 bb = ((const float2*)b1)[lane];
    const float h0 = fmaxf(fmaf(s0, inv, rr.x + bb.x), 0.f);
    const float h1 = fmaxf(fmaf(s1, inv, rr.y + bb.y), 0.f);
    const float4 w0 = wsm[2 * lane], w1 = wsm[2 * lane + 1];
    const float4 q0 = wsm[128 + 2 * lane], q1 = wsm[128 + 2 * lane + 1];
    float u0 = h0 * w0.x + h1 * w1.x;
    float u1 = h0 * w0.y + h1 * w1.y;
    float u2 = h0 * w0.z + h1 * w1.z;
    float v0 = h0 * q0.x + h1 * q1.x;
    float v1 = h0 * q0.y + h1 * q1.y;
    float v2 = h0 * q0.z + h1 * q1.z;
    #pragma unroll
    for (int off = 32; off; off >>= 1) {
        u0 += __shfl_xor(u0, off); u1 += __shfl_xor(u1, off); u2 += __shfl_xor(u2, off);
        v0 += __shfl_xor(v0, off); v1 += __shfl_xor(v1, off); v2 += __shfl_xor(v2, off);
    }
    if (lane == 0) {
        u4[i] = make_float4(u0, u1, u2, 0.f);
        v4[i] = make_float4(v0, v1, v2, 0.f);
    }
}

// ---------------------------------------------------------------------------
// K3: y[i] = mean_j u[j] + v[i] + c   (3-wide second-hop aggregation)
// ---------------------------------------------------------------------------
__global__ __launch_bounds__(256) void k_ycomb(
    const float4* __restrict__ u4, const float4* __restrict__ v4,
    const int* __restrict__ nbr, const int* __restrict__ degi,
    const float* __restrict__ degf, const float4* __restrict__ wsm,
    float4* __restrict__ y4)
{
    const int hw = threadIdx.x >> 5;
    const int lane = threadIdx.x & 31;
    const int i = blockIdx.x * 8 + hw;
    const int d = degi[i];
    const float inv = 1.0f / degf[i];
    const int* lst = nbr + (size_t)i * CAP;
    float s0 = 0.f, s1 = 0.f, s2 = 0.f;
    for (int base = 0; base + lane < d; base += 32) {
        const float4 u = u4[lst[base + lane]];
        s0 += u.x; s1 += u.y; s2 += u.z;
    }
    #pragma unroll
    for (int off = 16; off; off >>= 1) {
        s0 += __shfl_xor(s0, off); s1 += __shfl_xor(s1, off); s2 += __shfl_xor(s2, off);
    }
    if (lane == 0) {
        const float4 v = v4[i];
        const float4 c = wsm[256];
        y4[i] = make_float4(fmaf(s0, inv, v.x + c.x),
                            fmaf(s1, inv, v.y + c.y),
                            fmaf(s2, inv, v.z + c.z), 0.f);
    }
}

// ---------------------------------------------------------------------------
// K4: out[i,j] = ||y_i - y_j||, tiled 32 i x 1024 j per block.
// yi staged in LDS, 4 yj in registers, non-temporal float4 stores.
// ---------------------------------------------------------------------------
__global__ __launch_bounds__(256) void k_cdist(
    const float4* __restrict__ y4, float* __restrict__ out)
{
    __shared__ float4 yis[32];
    const int t = threadIdx.x;
    const int i0 = blockIdx.y * 32;
    if (t < 32) yis[t] = y4[i0 + t];
    __syncthreads();
    const int j0 = blockIdx.x * 1024 + t * 4;
    const float4 a0 = y4[j0 + 0], a1 = y4[j0 + 1];
    const float4 a2 = y4[j0 + 2], a3 = y4[j0 + 3];
    float* op = out + (size_t)i0 * NN + j0;
    #pragma unroll 4
    for (int ii = 0; ii < 32; ++ii) {
        const float4 yi = yis[ii];
        f32x4 r;
        { const float dx = yi.x - a0.x, dy = yi.y - a0.y, dz = yi.z - a0.z;
          r.x = sqrtf(fmaf(dx, dx, fmaf(dy, dy, dz * dz))); }
        { const float dx = yi.x - a1.x, dy = yi.y - a1.y, dz = yi.z - a1.z;
          r.y = sqrtf(fmaf(dx, dx, fmaf(dy, dy, dz * dz))); }
        { const float dx = yi.x - a2.x, dy = yi.y - a2.y, dz = yi.z - a2.z;
          r.z = sqrtf(fmaf(dx, dx, fmaf(dy, dy, dz * dz))); }
        { const float dx = yi.x - a3.x, dy = yi.y - a3.y, dz = yi.z - a3.z;
          r.w = sqrtf(fmaf(dx, dx, fmaf(dy, dy, dz * dz))); }
        __builtin_nontemporal_store(r, (f32x4*)op);
        op += NN;
    }
}

// ---------------------------------------------------------------------------
extern "C" void kernel_launch(void* const* d_in, const int* in_sizes, int n_in,
                              void* d_out, int out_size, void* d_ws, size_t ws_size,
                              hipStream_t stream) {
    const float* x   = (const float*)d_in[0];
    const float* adj = (const float*)d_in[1];
    const float* Wl1 = (const float*)d_in[2];
    const float* Wr1 = (const float*)d_in[3];
    const float* b1  = (const float*)d_in[4];
    const float* Wl2 = (const float*)d_in[5];
    const float* Wr2 = (const float*)d_in[6];
    const float* b2  = (const float*)d_in[7];
    const float* Wd  = (const float*)d_in[8];
    const float* bd  = (const float*)d_in[9];
    float* out = (float*)d_out;

    // ---- workspace layout (16B-aligned slots) ----
    char* ws = (char*)d_ws;
    const size_t nbr_b  = (size_t)NN * CAP * 4;    // 4 MB
    const size_t deg_b  = (size_t)NN * 4;          // 32 KB each
    const size_t vec_b  = (size_t)NN * 16;         // 128 KB each (u4,v4,y4)
    const size_t wsm_b  = 272 * 16;
    const size_t small_total = nbr_b + 2 * deg_b + 3 * vec_b + wsm_b;
    const size_t xl_b = (size_t)NN * HD * 4;       // 4 MB each

    size_t off = 0;
    int*    nbr  = (int*)(ws + off);    off += nbr_b;
    int*    degi = (int*)(ws + off);    off += deg_b;
    float*  degf = (float*)(ws + off);  off += deg_b;
    float4* u4   = (float4*)(ws + off); off += vec_b;
    float4* v4   = (float4*)(ws + off); off += vec_b;
    float4* y4   = (float4*)(ws + off); off += vec_b;
    float4* wsm  = (float4*)(ws + off); off += wsm_b;

    // xl/xr: in ws if it fits, else carve from d_out (dead before k_cdist).
    char* big = (ws_size >= small_total + 2 * xl_b) ? (ws + off) : (char*)d_out;
    float* xl = (float*)(big);
    float* xr = (float*)(big + xl_b);

    // ---- pipeline ----
    k_front<<<2561, 256, 0, stream>>>(
        x, Wl1, Wr1, adj, Wl2, Wr2, b2, Wd, bd,
        xl, xr, nbr, degi, degf, wsm);

    k_agg_proj<<<NN / 4, 256, 0, stream>>>(xl, xr, b1, nbr, degi, degf,
                                           wsm, u4, v4);

    k_ycomb<<<NN / 8, 256, 0, stream>>>(u4, v4, nbr, degi, degf, wsm, y4);

    k_cdist<<<dim3(NN / 1024, NN / 32), 256, 0, stream>>>(y4, out);
}